// Round 1
// 243.172 us; speedup vs baseline: 1.0346x; 1.0346x over previous
//
#include <hip/hip_runtime.h>
#include <hip/hip_bf16.h>
#include <math.h>

#define N_POINTS 1000000
#define N_GRIDS  16
#define LOG2_T   19
#define TABLE_MASK ((1u << LOG2_T) - 1u)
#define NBLOCKS  ((N_POINTS + 255) / 256)
#define CONV_BLOCKS 4096
#define FUSED_BLOCKS 2048          // multiple of 8; 8 groups -> 8 XCDs
#define N_ENTRIES (N_GRIDS << LOG2_T)   // 8.4M bf16x2 entries

struct ResArr { float r[N_GRIDS]; };

__device__ __forceinline__ unsigned pack_bf16x2(float a, float b)
{
    __hip_bfloat16 ha = __float2bfloat16(a);
    __hip_bfloat16 hb = __float2bfloat16(b);
    unsigned short ua = *(unsigned short*)&ha;
    unsigned short ub = *(unsigned short*)&hb;
    return (unsigned)ua | ((unsigned)ub << 16);
}

__device__ __forceinline__ float2 unpack_bf16x2(unsigned v)
{
    unsigned lo = (v & 0xffffu) << 16;
    unsigned hi = v & 0xffff0000u;
    return make_float2(__uint_as_float(lo), __uint_as_float(hi));
}

// gather from a packed-bf16x2 table: 3 phases (addr / 8 clustered loads / fma)
// so the compiler keeps all 8 gathers in flight before the first consume.
__device__ __forceinline__ void gather_level_bf16(
    float x0, float x1, float x2, float r,
    const unsigned* __restrict__ tbl, float& c0, float& c1)
{
    // match reference: (x + 1.0) * 0.5 * r, left-to-right fp32
    const float xn0 = (x0 + 1.0f) * 0.5f * r;
    const float xn1 = (x1 + 1.0f) * 0.5f * r;
    const float xn2 = (x2 + 1.0f) * 0.5f * r;
    const float f0 = floorf(xn0), f1 = floorf(xn1), f2 = floorf(xn2);
    const unsigned v0 = (unsigned)(int)f0;
    const unsigned v1 = (unsigned)(int)f1;
    const unsigned v2 = (unsigned)(int)f2;
    const float w0 = xn0 - f0, w1 = xn1 - f1, w2 = xn2 - f2;

    unsigned fv[8];
    #pragma unroll
    for (int k = 0; k < 8; ++k) {
        const unsigned vx = v0 + ((k >> 2) & 1);
        const unsigned vy = v1 + ((k >> 1) & 1);
        const unsigned vz = v2 + (k & 1);
        unsigned h = vx ^ (vy * 2654435761u) ^ (vz * 805459861u);
        fv[k] = tbl[h & TABLE_MASK];
    }
    c0 = 0.f; c1 = 0.f;
    #pragma unroll
    for (int k = 0; k < 8; ++k) {
        const float wgt = ((k & 4) ? w0 : 1.0f - w0) *
                          ((k & 2) ? w1 : 1.0f - w1) *
                          ((k & 1) ? w2 : 1.0f - w2);
        const float2 f = unpack_bf16x2(fv[k]);
        c0 += wgt * f.x;
        c1 += wgt * f.y;
    }
}

// ---- pass 0: fat kernel = table fp32->bf16x2 convert  ||  in-box compaction.
// The two halves are independent; merging removes a dispatch and overlaps
// the table-read stream with the point-read stream.
__global__ __launch_bounds__(256)
void prep_kernel(const float* __restrict__ tables, unsigned* __restrict__ tb,
                 const float* __restrict__ x, int* __restrict__ rank,
                 float4* __restrict__ xw, unsigned* __restrict__ counter)
{
    if (blockIdx.x < CONV_BLOCKS) {
        // ---- convert: fp32 tables -> packed bf16x2 (halves gather footprint)
        const unsigned nthr = CONV_BLOCKS * 256;
        for (unsigned e4 = blockIdx.x * 256 + threadIdx.x; e4 < (N_ENTRIES / 4);
             e4 += nthr) {
            const float4 a = ((const float4*)tables)[2 * e4];
            const float4 b = ((const float4*)tables)[2 * e4 + 1];
            uint4 o;
            o.x = pack_bf16x2(a.x, a.y);
            o.y = pack_bf16x2(a.z, a.w);
            o.z = pack_bf16x2(b.x, b.y);
            o.w = pack_bf16x2(b.z, b.w);
            ((uint4*)tb)[e4] = o;
        }
    } else {
        // ---- compact in-box points
        __shared__ unsigned woff[4];
        __shared__ unsigned base;
        const int t = threadIdx.x;
        const int p = (blockIdx.x - CONV_BLOCKS) * 256 + t;
        float x0 = 2.f, x1 = 2.f, x2 = 2.f;
        if (p < N_POINTS) {
            x0 = x[3 * p]; x1 = x[3 * p + 1]; x2 = x[3 * p + 2];
        }
        const bool inbox = (x0 >= -1.f) & (x0 <= 1.f) &
                           (x1 >= -1.f) & (x1 <= 1.f) &
                           (x2 >= -1.f) & (x2 <= 1.f);
        const unsigned long long m = __ballot(inbox);
        const int lane = t & 63, w = t >> 6;
        const unsigned prefix = __popcll(m & ((1ull << lane) - 1ull));
        if (lane == 0) woff[w] = (unsigned)__popcll(m);
        __syncthreads();
        if (t == 0) {
            unsigned s = 0;
            #pragma unroll
            for (int i = 0; i < 4; ++i) { unsigned v = woff[i]; woff[i] = s; s += v; }
            base = atomicAdd(counter, s);
        }
        __syncthreads();
        if (p < N_POINTS) {
            if (inbox) {
                const unsigned rk = base + woff[w] + prefix;
                rank[p] = (int)rk;
                xw[rk] = make_float4(x0, x1, x2, 0.f);
            } else {
                rank[p] = -1;
            }
        }
    }
}

// ---- pass 1: 2 levels per XCD group, paired (k, 15-k) -----------------------
// The hash scatters even coarse tables over the full 2 MiB slot range, so
// per-level touched-line footprints are L0~0.3MB ... L4+~2MB. The old
// "coarse by points + fine by tasks" schedule gave each XCD a ~10 MB working
// set -> L2 thrash (FETCH 157 MB vs ~45 MB ideal). Pairing (k,15-k) gives
// every group exactly 2 levels (perfect static balance: identical request
// counts) with a 2.3-4 MB footprint; sequential per-level passes keep only
// one ~2 MB table hot at a time.
__global__ __launch_bounds__(256)
void fused_levels_kernel(const float4* __restrict__ xw,
                         const unsigned* __restrict__ counter,
                         const unsigned* __restrict__ tb,
                         unsigned* __restrict__ ws2, ResArr res)
{
    const unsigned k    = blockIdx.x & 7;
    const unsigned bix  = blockIdx.x >> 3;
    const unsigned nbx  = gridDim.x >> 3;
    const unsigned cnt  = *counter;
    const unsigned tid0 = bix * 256 + threadIdx.x;
    const unsigned stride = nbx * 256;

    #pragma unroll 1
    for (int t = 0; t < 2; ++t) {
        const int g = t ? (15 - (int)k) : (int)k;   // no array -> no scratch
        const float r = res.r[g];
        const unsigned* __restrict__ tbl = tb + ((size_t)g << LOG2_T);
        unsigned* __restrict__ wrow = ws2 + (size_t)g * N_POINTS;
        for (unsigned i = tid0; i < cnt; i += stride) {
            const float4 v = xw[i];
            float c0, c1;
            gather_level_bf16(v.x, v.y, v.z, r, tbl, c0, c1);
            wrow[i] = pack_bf16x2(c0, c1);
        }
    }
}

// ---- pass 2: transpose with instruction-coalesced writes -------------------
__global__ __launch_bounds__(256)
void tail_kernel(const int* __restrict__ rank, const unsigned* __restrict__ ws2,
                 float* __restrict__ out)
{
    const int t = threadIdx.x;
    const int c = blockIdx.x;
    const int P0 = c * 256;
    float4* __restrict__ out4 = (float4*)out + (size_t)P0 * 8;

    #pragma unroll
    for (int i = 0; i < 8; ++i) {
        const int j  = i * 256 + t;      // float4 index within chunk
        const int pp = P0 + (j >> 3);    // global point index
        const int q  = j & 7;            // feature quad -> levels 2q, 2q+1
        if (pp < N_POINTS) {
            const int rk = rank[pp];
            float4 v = make_float4(0.f, 0.f, 0.f, 0.f);
            if (rk >= 0) {
                const float2 fa = unpack_bf16x2(ws2[(size_t)(2 * q) * N_POINTS + rk]);
                const float2 fb = unpack_bf16x2(ws2[(size_t)(2 * q + 1) * N_POINTS + rk]);
                v = make_float4(fa.x, fa.y, fb.x, fb.y);
            }
            out4[j] = v;
        }
    }
}

// ---- fallback (ws too small): R1-style monolithic kernel (fp32 tables) -----
__device__ __forceinline__ void gather_level_f32(
    float x0, float x1, float x2, float r,
    const float2* __restrict__ tbl, float& c0, float& c1)
{
    const float xn0 = (x0 + 1.0f) * 0.5f * r;
    const float xn1 = (x1 + 1.0f) * 0.5f * r;
    const float xn2 = (x2 + 1.0f) * 0.5f * r;
    const float f0 = floorf(xn0), f1 = floorf(xn1), f2 = floorf(xn2);
    const unsigned v0 = (unsigned)(int)f0;
    const unsigned v1 = (unsigned)(int)f1;
    const unsigned v2 = (unsigned)(int)f2;
    const float w0 = xn0 - f0, w1 = xn1 - f1, w2 = xn2 - f2;
    c0 = 0.f; c1 = 0.f;
    #pragma unroll
    for (int k = 0; k < 8; ++k) {
        const unsigned vx = v0 + ((k >> 2) & 1);
        const unsigned vy = v1 + ((k >> 1) & 1);
        const unsigned vz = v2 + (k & 1);
        unsigned h = (vx * 1u) ^ (vy * 2654435761u) ^ (vz * 805459861u);
        h &= TABLE_MASK;
        const float wgt = ((k & 4) ? w0 : 1.0f - w0) *
                          ((k & 2) ? w1 : 1.0f - w1) *
                          ((k & 1) ? w2 : 1.0f - w2);
        const float2 f = tbl[h];
        c0 += wgt * f.x;
        c1 += wgt * f.y;
    }
}

__global__ __launch_bounds__(256)
void mono_kernel(const float* __restrict__ x, const float* __restrict__ tables,
                 float* __restrict__ out, ResArr res)
{
    int idx = blockIdx.x * blockDim.x + threadIdx.x;
    if (idx >= N_POINTS * N_GRIDS) return;
    int b = idx >> 4, g = idx & 15;
    float x0 = x[b * 3], x1 = x[b * 3 + 1], x2 = x[b * 3 + 2];
    bool inbox = (x0 >= -1.f) & (x0 <= 1.f) & (x1 >= -1.f) & (x1 <= 1.f) &
                 (x2 >= -1.f) & (x2 <= 1.f);
    float c0 = 0.f, c1 = 0.f;
    if (inbox) {
        const float2* tbl = (const float2*)tables + ((size_t)g << LOG2_T);
        gather_level_f32(x0, x1, x2, res.r[g], tbl, c0, c1);
    }
    ((float2*)out)[(size_t)b * N_GRIDS + g] = make_float2(c0, c1);
}

extern "C" void kernel_launch(void* const* d_in, const int* in_sizes, int n_in,
                              void* d_out, int out_size, void* d_ws, size_t ws_size,
                              hipStream_t stream)
{
    const float* x      = (const float*)d_in[0];
    const float* tables = (const float*)d_in[1];
    float* out          = (float*)d_out;

    ResArr res;
    double pls = exp((log(2048.0) - log(16.0)) / 15.0);
    for (int i = 0; i < N_GRIDS; ++i)
        res.r[i] = (float)floor(16.0 * pow(pls, (double)i));

    // ws layout: [counter 256 B][rank 4 MB][xw 16 MB][ws2 64 MB][tb 33.6 MB]
    const size_t off_rank = 256;
    const size_t off_xw   = off_rank + (size_t)N_POINTS * 4;
    const size_t off_ws2  = off_xw + (size_t)N_POINTS * 16;
    const size_t off_tb   = off_ws2 + (size_t)N_GRIDS * N_POINTS * 4;
    const size_t ws_needed = off_tb + (size_t)N_ENTRIES * 4;

    if (ws_size < ws_needed) {
        int total = N_POINTS * N_GRIDS;
        mono_kernel<<<(total + 255) / 256, 256, 0, stream>>>(x, tables, out, res);
        return;
    }

    char* w = (char*)d_ws;
    unsigned* counter = (unsigned*)w;
    int*      rank    = (int*)(w + off_rank);
    float4*   xw      = (float4*)(w + off_xw);
    unsigned* ws2     = (unsigned*)(w + off_ws2);
    unsigned* tb      = (unsigned*)(w + off_tb);

    (void)hipMemsetAsync(counter, 0, 256, stream);
    prep_kernel<<<CONV_BLOCKS + NBLOCKS, 256, 0, stream>>>(tables, tb,
                                                           x, rank, xw, counter);
    fused_levels_kernel<<<FUSED_BLOCKS, 256, 0, stream>>>(xw, counter, tb,
                                                          ws2, res);
    tail_kernel<<<NBLOCKS, 256, 0, stream>>>(rank, ws2, out);
}